// Round 19
// baseline (244.620 us; speedup 1.0000x reference)
//
#include <hip/hip_runtime.h>
#include <hip/hip_bf16.h>
#include <stdint.h>

#define DM 1024   // d_model
#define DD 512    // d (proj out / head dim)
#define BB 32     // batch
#define LL 1024   // seq len
#define SCALE 0.04419417382415922f  // 1/sqrt(512)
#define MAT ((size_t)BB * LL * DD)  // elems per q/k/v matrix

typedef float f32x4 __attribute__((ext_vector_type(4)));
typedef float f32x16 __attribute__((ext_vector_type(16)));
typedef short bf16x8 __attribute__((ext_vector_type(8)));
typedef short bf16x4 __attribute__((ext_vector_type(4)));

__device__ inline unsigned short f2bf(float f) {
    union { float f; uint32_t u; } v; v.f = f;
    uint32_t r = v.u + 0x7fffu + ((v.u >> 16) & 1u);
    return (unsigned short)(r >> 16);
}
__device__ inline float bf2f(unsigned short u) {
    union { uint32_t u; float f; } v; v.u = ((uint32_t)u) << 16;
    return v.f;
}

__device__ inline bf16x4 cvt4(f32x4 a, float s) {
    bf16x4 r;
    r[0] = (short)f2bf(a[0] * s);
    r[1] = (short)f2bf(a[1] * s);
    r[2] = (short)f2bf(a[2] * s);
    r[3] = (short)f2bf(a[3] * s);
    return r;
}

#define GLOAD_LDS16(gsrc, ldst) \
    __builtin_amdgcn_global_load_lds((const __attribute__((address_space(1))) unsigned int*)(gsrc), \
        (__attribute__((address_space(3))) unsigned int*)(ldst), 16, 0, 0)

__device__ inline void publish_barrier() {
    asm volatile("s_waitcnt vmcnt(0)" ::: "memory");
    __builtin_amdgcn_sched_barrier(0);
    __builtin_amdgcn_s_barrier();
    __builtin_amdgcn_sched_barrier(0);
}
__device__ inline void gate8() {
    asm volatile("s_waitcnt vmcnt(8)" ::: "memory");
    __builtin_amdgcn_sched_barrier(0);
    __builtin_amdgcn_s_barrier();
    __builtin_amdgcn_sched_barrier(0);
}
__device__ inline void gate6() {
    asm volatile("s_waitcnt vmcnt(6)" ::: "memory");
    __builtin_amdgcn_sched_barrier(0);
    __builtin_amdgcn_s_barrier();
    __builtin_amdgcn_sched_barrier(0);
}
__device__ inline void gate2() {
    asm volatile("s_waitcnt vmcnt(2)" ::: "memory");
    __builtin_amdgcn_sched_barrier(0);
    __builtin_amdgcn_s_barrier();
    __builtin_amdgcn_sched_barrier(0);
}
__device__ inline void gate0() {
    asm volatile("s_waitcnt vmcnt(0)" ::: "memory");
    __builtin_amdgcn_sched_barrier(0);
    __builtin_amdgcn_s_barrier();
    __builtin_amdgcn_sched_barrier(0);
}

// ---------------------------------------------------------------------------
// Kernel 0: fused casts, grid-stride over 2048 blocks.
// ---------------------------------------------------------------------------
#define NCHUNK (16384 * 256 + 768 * 256)
__global__ __launch_bounds__(256) void cast_all(const float* __restrict__ x,
                                                const float* __restrict__ Wq,
                                                const float* __restrict__ Wk,
                                                const float* __restrict__ Wv,
                                                unsigned short* __restrict__ xb,
                                                unsigned short* __restrict__ Wb)
{
    for (size_t idx = (size_t)blockIdx.x * 256 + threadIdx.x; idx < NCHUNK;
         idx += (size_t)2048 * 256) {
        if (idx < (size_t)16384 * 256) {
            size_t base = idx * 8;
            f32x4 a = *(const f32x4*)(x + base);
            f32x4 b = *(const f32x4*)(x + base + 4);
            bf16x4 lo = cvt4(a, 1.0f), hi = cvt4(b, 1.0f);
            bf16x8 o = {lo[0], lo[1], lo[2], lo[3], hi[0], hi[1], hi[2], hi[3]};
            *(bf16x8*)(xb + base) = o;
        } else {
            size_t wi = idx - (size_t)16384 * 256;
            int o = (int)(wi >> 16);
            size_t rem = wi & 65535;
            const float* W = (o == 0) ? Wq : (o == 1) ? Wk : Wv;
            float s = (o == 0) ? SCALE : 1.0f;
            size_t base = rem * 8;
            f32x4 a = *(const f32x4*)(W + base);
            f32x4 b = *(const f32x4*)(W + base + 4);
            bf16x4 lo = cvt4(a, s), hi = cvt4(b, s);
            bf16x8 out = {lo[0], lo[1], lo[2], lo[3], hi[0], hi[1], hi[2], hi[3]};
            *(bf16x8*)(Wb + (size_t)o * 524288 + base) = out;
        }
    }
}

// ---------------------------------------------------------------------------
// Kernel 1: q/k/v projection v7 — r18's 2-gate counted-vmcnt structure with
// MFMA switched to v_mfma_f32_32x32x16_bf16 (ceiling 2495 vs 2176 TF; half
// the MFMA instructions per phase). Staging/swizzle/gates/LDS image are
// byte-identical to v6c; only frag reads, MFMA calls, and the C/D epilogue
// mapping change. Frag mapping: A/B row = lane&31, k-octet = lane>>5;
// C/D: col = lane&31, row = (reg&3) + 8*(reg>>2) + 4*(lane>>5) [m74/m101].
// Per-wave output 128x64 = 4 m-tiles x 2 n-tiles of 32x32 (acc[4][2] f32x16
// = 128 regs, same as before). V output (o==2): LDS-transpose epilogue.
// ---------------------------------------------------------------------------
__global__ __launch_bounds__(512, 2) void qkv_proj7(
    const unsigned short* __restrict__ xb,
    const unsigned short* __restrict__ Wb,
    const float* __restrict__ bq, const float* __restrict__ bk, const float* __restrict__ bv,
    unsigned short* __restrict__ qkv,     // q at 0, k at MAT
    unsigned short* __restrict__ vt)      // [b][d][l]
{
    __shared__ __align__(16) unsigned short AL[2][2][8192];
    __shared__ __align__(16) unsigned short BL[2][2][8192];

    const int o = blockIdx.y;
    const float* bias = (o == 0) ? bq : (o == 1) ? bk : bv;
    const float wscale = (o == 0) ? SCALE : 1.0f;
    const unsigned short* W = Wb + (size_t)o * 524288;
    unsigned short* out = qkv + (size_t)o * MAT;

    int wg = blockIdx.x;
    wg = (wg & 7) * 32 + (wg >> 3);
    const int mt = wg >> 1, nt = wg & 1;
    const int rowbase = mt * 256;
    const int colbase = nt * 256;

    const int tid  = threadIdx.x;
    const int lane = tid & 63;
    const int w    = tid >> 6;
    const int wm   = w >> 2;                // 0..1: 64-row group within each half
    const int wn   = w & 3;                 // 0..3: 32-col group within each half
    const int l31  = lane & 31, l5 = lane >> 5;
    const int rx   = lane & 7;              // row&7 for all frag rows

    const int r8   = lane >> 3;
    const int swch = (lane & 7) ^ r8;

    const char* xpanel = (const char*)(xb + (size_t)rowbase * DM);
    const char* wpanel = (const char*)(W  + (size_t)colbase * DM);

    #define STAGE_HALF(panel, T, H, slot) do {                                   \
        _Pragma("unroll")                                                        \
        for (int i2 = 0; i2 < 2; ++i2) {                                         \
            int grp = i2 * 8 + w;                                                \
            GLOAD_LDS16((panel) + ((size_t)((H) * 128 + grp * 8 + r8) * 2048)    \
                            + (size_t)(T) * 128 + swch * 16,                     \
                        (char*)(slot) + grp * 1024);                             \
        }                                                                        \
    } while (0)

    // 32x32x16 frag reads from the swizzled LDS image
    #define RDA32(base, m2, ks) (*(const bf16x8*)((base) + (wm * 64 + (m2) * 32 + l31) * 128 \
                            + ((((ks) * 2 + l5) ^ rx) << 4)))
    #define RDB32(base, ks)     (*(const bf16x8*)((base) + (wn * 32 + l31) * 128 \
                            + ((((ks) * 2 + l5) ^ rx) << 4)))

    f32x16 acc[4][2];
    #pragma unroll
    for (int i = 0; i < 4; ++i)
        #pragma unroll
        for (int j = 0; j < 2; ++j)
            acc[i][j] = (f32x16){0.f, 0.f, 0.f, 0.f, 0.f, 0.f, 0.f, 0.f,
                                 0.f, 0.f, 0.f, 0.f, 0.f, 0.f, 0.f, 0.f};

    bf16x8 aF[2][4], bF[2][4];   // [tile][kstep]

    STAGE_HALF(xpanel, 0, 0, &AL[0][0][0]);   // A0(0)
    STAGE_HALF(wpanel, 0, 0, &BL[0][0][0]);   // B0(0)
    STAGE_HALF(wpanel, 0, 1, &BL[0][1][0]);   // B1(0)
    STAGE_HALF(xpanel, 0, 1, &AL[0][1][0]);   // A1(0)

    for (int t = 0; t < 16; ++t) {
        const int c = t & 1, cn = c ^ 1;
        const char* A0b = (const char*)&AL[c][0][0];
        const char* A1b = (const char*)&AL[c][1][0];
        const char* B0b = (const char*)&BL[c][0][0];
        const char* B1b = (const char*)&BL[c][1][0];
        const bool st = (t < 15);

        // ---- phase 0+1: A-half0 x (B-half0, B-half1) ----
        if (st) {
            STAGE_HALF(xpanel, t + 1, 0, &AL[cn][0][0]);
            STAGE_HALF(wpanel, t + 1, 0, &BL[cn][0][0]);
            gate6();
        } else gate2();
        #pragma unroll
        for (int ks = 0; ks < 4; ++ks) {
            aF[0][ks] = RDA32(A0b, 0, ks);
            aF[1][ks] = RDA32(A0b, 1, ks);
            bF[0][ks] = RDB32(B0b, ks);
            bF[1][ks] = RDB32(B1b, ks);
        }
        #pragma unroll
        for (int ks = 0; ks < 4; ++ks)
            #pragma unroll
            for (int ni = 0; ni < 2; ++ni)
                #pragma unroll
                for (int m2 = 0; m2 < 2; ++m2)
                    acc[m2][ni] = __builtin_amdgcn_mfma_f32_32x32x16_bf16(
                        aF[m2][ks], bF[ni][ks], acc[m2][ni], 0, 0, 0);

        // ---- phase 2+3: A-half1 x (B-half0, B-half1) ----
        if (st) {
            STAGE_HALF(wpanel, t + 1, 1, &BL[cn][1][0]);
            STAGE_HALF(xpanel, t + 1, 1, &AL[cn][1][0]);
            gate8();
        } else gate0();
        #pragma unroll
        for (int ks = 0; ks < 4; ++ks) {
            aF[0][ks] = RDA32(A1b, 0, ks);
            aF[1][ks] = RDA32(A1b, 1, ks);
        }
        #pragma unroll
        for (int ks = 0; ks < 4; ++ks)
            #pragma unroll
            for (int ni = 0; ni < 2; ++ni)
                #pragma unroll
                for (int m2 = 0; m2 < 2; ++m2)
                    acc[2 + m2][ni] = __builtin_amdgcn_mfma_f32_32x32x16_bf16(
                        aF[m2][ks], bF[ni][ks], acc[2 + m2][ni], 0, 0, 0);
    }
    #undef STAGE_HALF
    #undef RDA32
    #undef RDB32

    if (o != 2) {
        // C/D: col = l31, row = (reg&3) + 8*(reg>>2) + 4*l5
        #pragma unroll
        for (int mi = 0; mi < 4; ++mi) {
            int rbase = rowbase + (mi >> 1) * 128 + wm * 64 + (mi & 1) * 32 + 4 * l5;
            #pragma unroll
            for (int ni = 0; ni < 2; ++ni) {
                int col = colbase + ni * 128 + wn * 32 + l31;
                float bv_ = bias[col] * wscale;
                #pragma unroll
                for (int q = 0; q < 4; ++q) {
                    int row0 = rbase + 8 * q;
                    #pragma unroll
                    for (int r2 = 0; r2 < 4; ++r2)
                        out[(size_t)(row0 + r2) * DD + col] = f2bf(acc[mi][ni][q * 4 + r2] + bv_);
                }
            }
        }
    } else {
        // ---- V epilogue: transpose 256x256 tile via LDS -> vt[b][d][l] ----
        unsigned short* ldsT = (unsigned short*)&AL[0][0][0];
        const int bidx  = rowbase >> 10;
        const int lbase = rowbase & 1023;
        #pragma unroll
        for (int p = 0; p < 4; ++p) {
            __syncthreads();
            #pragma unroll
            for (int ni = 0; ni < 2; ++ni) {
                int cb = ni * 128 + wn * 32;          // col-block base (within 256)
                if ((cb >> 6) == p) {
                    int cc = cb - p * 64 + l31;        // 0..63
                    float bv_ = bias[colbase + cb + l31];
                    #pragma unroll
                    for (int mi = 0; mi < 4; ++mi) {
                        int rbase = (mi >> 1) * 128 + wm * 64 + (mi & 1) * 32 + 4 * l5;
                        #pragma unroll
                        for (int q = 0; q < 4; ++q) {
                            int rowl = rbase + 8 * q;
                            bf16x4 v4;
                            #pragma unroll
                            for (int r2 = 0; r2 < 4; ++r2)
                                v4[r2] = (short)f2bf(acc[mi][ni][q * 4 + r2] + bv_);
                            *(bf16x4*)&ldsT[cc * 264 + rowl] = v4;
                        }
                    }
                }
            }
            __syncthreads();
            #pragma unroll
            for (int it = 0; it < 4; ++it) {
                int uu = tid + it * 512;
                int cc = uu >> 5;
                int r0 = (uu & 31) * 8;
                bf16x8 val = *(const bf16x8*)&ldsT[cc * 264 + r0];
                int dg = colbase + p * 64 + cc;
                *(bf16x8*)(vt + ((size_t)(bidx * DD + dg)) * LL + lbase + r0) = val;
            }
        }
    }
}

// ---------------------------------------------------------------------------
// Kernel 3: S = q . k^T, lower-triangle 128x128 tiles (unchanged).
// ---------------------------------------------------------------------------
__global__ __launch_bounds__(256, 2) void sgemm_qk(
    const unsigned short* __restrict__ qkv,
    unsigned short* __restrict__ S)
{
    __shared__ __align__(16) unsigned short At[2][8192];
    __shared__ __align__(16) unsigned short Bt[2][8192];

    int wg = blockIdx.x;
    wg = (wg & 7) * 144 + (wg >> 3);
    const int b = wg / 36;
    const int t36 = wg % 36;
    int mt = 0, accq = 0;
    while (accq + mt + 1 <= t36) { ++mt; accq += mt; }
    const int nt = t36 - accq;

    const int tid  = threadIdx.x;
    const int lane = tid & 63;
    const int w    = tid >> 6;
    const int wr   = (w >> 1) * 64;
    const int wc   = (w & 1) * 64;
    const int l15  = lane & 15, l4 = lane >> 4;

    const int r8   = lane >> 3;
    const int swch = (lane & 7) ^ r8;

    const unsigned short* q = qkv;
    const unsigned short* k = qkv + MAT;
    const char* apanel = (const char*)(q + ((size_t)(b * LL) + mt * 128) * DD);
    const char* bpanel = (const char*)(k + ((size_t)(b * LL) + nt * 128) * DD);

    f32x4 acc[4][4];
    #pragma unroll
    for (int i = 0; i < 4; ++i)
        #pragma unroll
        for (int j = 0; j < 4; ++j)
            acc[i][j] = (f32x4){0.f, 0.f, 0.f, 0.f};

    #define STAGE_QK(KK, BUF) do {                                               \
        _Pragma("unroll")                                                        \
        for (int i2 = 0; i2 < 4; ++i2) {                                         \
            int grp = i2 * 4 + w;                                                \
            size_t rowoff = (size_t)(grp * 8 + r8) * 1024 + (KK) * 2 + swch * 16;\
            GLOAD_LDS16(apanel + rowoff, (char*)&At[BUF][0] + grp * 1024);       \
            GLOAD_LDS16(bpanel + rowoff, (char*)&Bt[BUF][0] + grp * 1024);       \
        }                                                                        \
    } while (0)

    STAGE_QK(0, 0);
    __syncthreads();

    for (int t = 0; t < 8; ++t) {
        const int cur = t & 1;
        if (t < 7) STAGE_QK((t + 1) * 64, cur ^ 1);

        const char* Ab = (const char*)&At[cur][0];
        const char* Bb = (const char*)&Bt[cur][0];
        #pragma unroll
        for (int ks = 0; ks < 2; ++ks) {
            bf16x8 af[4], bf_[4];
            const int ch = (ks * 2 + l4 / 2) * 0 + ((ks * 4 + l4) ^ (l15 & 7));
            #pragma unroll
            for (int m = 0; m < 4; ++m)
                af[m] = *(const bf16x8*)(Ab + (wr + m * 16 + l15) * 128 + (ch << 4));
            #pragma unroll
            for (int n = 0; n < 4; ++n)
                bf_[n] = *(const bf16x8*)(Bb + (wc + n * 16 + l15) * 128 + (ch << 4));
            #pragma unroll
            for (int n = 0; n < 4; ++n)
                #pragma unroll
                for (int m = 0; m < 4; ++m)
                    acc[m][n] = __builtin_amdgcn_mfma_f32_16x16x32_bf16(af[m], bf_[n], acc[m][n], 0, 0, 0);
        }

        if (t < 7) publish_barrier();
    }
    #undef STAGE_QK

    unsigned short* sp = S + ((size_t)(b * LL) + mt * 128) * LL + nt * 128;
    #pragma unroll
    for (int n = 0; n < 4; ++n) {
        int col = wc + n * 16 + l15;
        #pragma unroll
        for (int m = 0; m < 4; ++m) {
            int row0 = wr + m * 16 + l4 * 4;
            #pragma unroll
            for (int r = 0; r < 4; ++r)
                sp[(size_t)(row0 + r) * LL + col] = f2bf(acc[m][n][r]);
        }
    }
}

// ---------------------------------------------------------------------------
// Kernel 4: row softmax v2 (unchanged).
// ---------------------------------------------------------------------------
__global__ __launch_bounds__(256) void softmax_rows(
    const unsigned short* __restrict__ S,
    const int* __restrict__ mask,
    unsigned short* __restrict__ P)
{
    __shared__ float mbias[1024];
    const int rc = blockIdx.x, b = blockIdx.y;
    const int tid = threadIdx.x, lane = tid & 63, w = tid >> 6;

    {
        const int* mp = mask + b * LL;
        #pragma unroll
        for (int j = 0; j < 4; ++j)
            mbias[tid * 4 + j] = mp[tid * 4 + j] ? 0.0f : -1e30f;
    }
    __syncthreads();

    const int j0 = lane * 16;
    const int limit = ((rc >> 2) + 1) << 7;
    for (int i = 0; i < 8; ++i) {
        const int r = rc * 32 + i * 4 + w;
        const unsigned short* srow = S + ((size_t)(b * LL) + r) * LL;

        bf16x8 v0 = {0,0,0,0,0,0,0,0}, v1 = {0,0,0,0,0,0,0,0};
        if (j0 <= r)     v0 = *(const bf16x8*)(srow + j0);
        if (j0 + 8 <= r) v1 = *(const bf16x8*)(srow + j0 + 8);

        float s[16];
        #pragma unroll
        for (int e = 0; e < 8; ++e) {
            int j = j0 + e;
            s[e]     = (j <= r)     ? bf2f((unsigned short)v0[e]) + mbias[j]     : -3e38f;
            s[8 + e] = (j + 8 <= r) ? bf2f((unsigned short)v1[e]) + mbias[j + 8] : -3e38f;
        }
        float mx = s[0];
        #pragma unroll
        for (int e = 1; e < 16; ++e) mx = fmaxf(mx, s[e]);
        mx = fmaxf(mx, __shfl_xor(mx, 1));
        mx = fmaxf(mx, __shfl_xor(mx, 2));
        mx = fmaxf(mx, __shfl_xor(mx, 4));
        mx = fmaxf(mx, __shfl_xor(mx, 8));
        mx = fmaxf(mx, __shfl_xor(mx, 16));
        mx = fmaxf(mx, __shfl_xor(mx, 32));

        float p[16], ls = 0.f;
        #pragma unroll
        for (int e = 0; e < 16; ++e) { p[e] = __expf(s[e] - mx); ls += p[e]; }
        ls += __shfl_xor(ls, 1);
        ls += __shfl_xor(ls, 2);
        ls += __shfl_xor(ls, 4);
        ls += __shfl_xor(ls, 8);
        ls += __shfl_xor(ls, 16);
        ls += __shfl_xor(ls, 32);
        const float inv = 1.0f / ls;

        if (j0 < limit) {
            bf16x8 o0, o1;
            #pragma unroll
            for (int e = 0; e < 8; ++e) {
                o0[e] = (short)f2bf(p[e] * inv);
                o1[e] = (short)f2bf(p[8 + e] * inv);
            }
            unsigned short* prow = P + ((size_t)(b * LL) + r) * LL;
            *(bf16x8*)(prow + j0)     = o0;
            *(bf16x8*)(prow + j0 + 8) = o1;
        }
    }
}

// ---------------------------------------------------------------------------
// Kernel 5: O = relu(P . V) via vt (unchanged).
// ---------------------------------------------------------------------------
__global__ __launch_bounds__(256, 2) void pv_gemm(
    const unsigned short* __restrict__ P,
    const unsigned short* __restrict__ vt,
    float* __restrict__ outp)
{
    __shared__ __align__(16) unsigned short At[2][8192];
    __shared__ __align__(16) unsigned short Bt[2][8192];

    int wg = blockIdx.x;
    wg = (wg & 7) * 128 + (wg >> 3);
    const int b  = wg >> 5;
    const int rr = wg & 31;
    const int idx = rr >> 2;
    const int rt = (idx & 1) ? ((idx - 1) >> 1) : (7 - (idx >> 1));  // 7,0,6,1,5,2,4,3
    const int ct = rr & 3;

    const int tid  = threadIdx.x;
    const int lane = tid & 63;
    const int w    = tid >> 6;
    const int wr   = (w >> 1) * 64;
    const int wc   = (w & 1) * 64;
    const int l15  = lane & 15, l4 = lane >> 4;

    const int r8   = lane >> 3;
    const int swch = (lane & 7) ^ r8;

    const char* apanel = (const char*)(P  + ((size_t)(b * LL) + rt * 128) * LL);
    const char* bpanel = (const char*)(vt + ((size_t)(b * DD) + ct * 128) * LL);

    const int NT = (rt + 1) * 2;

    f32x4 acc[4][4];
    #pragma unroll
    for (int i = 0; i < 4; ++i)
        #pragma unroll
        for (int j = 0; j < 4; ++j)
            acc[i][j] = (f32x4){0.f, 0.f, 0.f, 0.f};

    #define STAGE_PV(KK, BUF) do {                                               \
        _Pragma("unroll")                                                        \
        for (int i2 = 0; i2 < 4; ++i2) {                                         \
            int grp = i2 * 4 + w;                                                \
            size_t rowoff = (size_t)(grp * 8 + r8) * 2048 + (KK) * 2 + swch * 16;\
            GLOAD_LDS16(apanel + rowoff, (char*)&At[BUF][0] + grp * 1024);       \
            GLOAD_LDS16(bpanel + rowoff, (char*)&Bt[BUF][0] + grp * 1024);       \
        }                                                                        \
    } while (0)

    STAGE_PV(0, 0);
    __syncthreads();

    for (int t = 0; t < NT; ++t) {
        const int cur = t & 1;
        if (t < NT - 1) STAGE_PV((t + 1) * 64, cur ^ 1);

        const char* Ab = (const char*)&At[cur][0];
        const char* Bb = (const char*)&Bt[cur][0];
        #pragma unroll
        for (int ks = 0; ks < 2; ++ks) {
            bf16x8 af[4], bf_[4];
            const int ch = (ks * 4 + l4) ^ (l15 & 7);
            #pragma unroll
            for (int m = 0; m < 4; ++m)
                af[m] = *(const bf16x8*)(Ab + (wr + m * 16 + l15) * 128 + (ch << 4));
            #pragma unroll
            for (int n = 0; n < 4; ++n)
                bf_[n] = *(const bf16x8*)(Bb + (wc + n * 16 + l15) * 128 + (ch << 4));
            #pragma unroll
            for (int n = 0; n < 4; ++n)
                #pragma unroll
                for (int m = 0; m < 4; ++m)
                    acc[m][n] = __builtin_amdgcn_mfma_f32_16x16x32_bf16(af[m], bf_[n], acc[m][n], 0, 0, 0);
        }

        if (t < NT - 1) publish_barrier();
    }
    #undef STAGE_PV

    float* op = outp + ((size_t)(b * LL) + rt * 128) * DD + ct * 128;
    #pragma unroll
    for (int n = 0; n < 4; ++n) {
        int col = wc + n * 16 + l15;
        #pragma unroll
        for (int m = 0; m < 4; ++m) {
            int row0 = wr + m * 16 + l4 * 4;
            #pragma unroll
            for (int r = 0; r < 4; ++r)
                op[(size_t)(row0 + r) * DD + col] = fmaxf(acc[m][n][r], 0.f);
        }
    }
}

extern "C" void kernel_launch(void* const* d_in, const int* in_sizes, int n_in,
                              void* d_out, int out_size, void* d_ws, size_t ws_size,
                              hipStream_t stream) {
    const float* x  = (const float*)d_in[0];
    const float* Wq = (const float*)d_in[1];
    const float* bq = (const float*)d_in[2];
    const float* Wk = (const float*)d_in[3];
    const float* bk = (const float*)d_in[4];
    const float* Wv = (const float*)d_in[5];
    const float* bv = (const float*)d_in[6];
    const int* mask = (const int*)d_in[7];

    unsigned short* qkv = (unsigned short*)d_ws;          // q | k (2 x 32MB)
    unsigned short* vtp = qkv + 2 * MAT;                  // vt [b][d][l] (32MB)
    unsigned short* Wb  = qkv + 3 * MAT;                  // W bf16 (3MB)
    unsigned short* xb  = (unsigned short*)d_out;         // x bf16 (64MB), dead after proj
    unsigned short* S   = (unsigned short*)d_out;         // S bf16 (64MB), overwrites xb
    unsigned short* Pp  = qkv;                            // P bf16 over q+k (dead)
    float* out = (float*)d_out;                           // final O overwrites S

    cast_all<<<2048, 256, 0, stream>>>(x, Wq, Wk, Wv, xb, Wb);
    qkv_proj7<<<dim3(256, 3), 512, 0, stream>>>(xb, Wb, bq, bk, bv, qkv, vtp);
    sgemm_qk<<<dim3(1152), 256, 0, stream>>>(qkv, S);
    softmax_rows<<<dim3(32, 32), 256, 0, stream>>>(S, mask, Pp);
    pv_gemm<<<dim3(1024), 256, 0, stream>>>(Pp, vtp, out);
}

// Round 20
// 234.424 us; speedup vs baseline: 1.0435x; 1.0435x over previous
//
#include <hip/hip_runtime.h>
#include <hip/hip_bf16.h>
#include <stdint.h>

#define DM 1024   // d_model
#define DD 512    // d (proj out / head dim)
#define BB 32     // batch
#define LL 1024   // seq len
#define SCALE 0.04419417382415922f  // 1/sqrt(512)
#define MAT ((size_t)BB * LL * DD)  // elems per q/k/v matrix

typedef float f32x4 __attribute__((ext_vector_type(4)));
typedef short bf16x8 __attribute__((ext_vector_type(8)));
typedef short bf16x4 __attribute__((ext_vector_type(4)));

__device__ inline unsigned short f2bf(float f) {
    union { float f; uint32_t u; } v; v.f = f;
    uint32_t r = v.u + 0x7fffu + ((v.u >> 16) & 1u);
    return (unsigned short)(r >> 16);
}
__device__ inline float bf2f(unsigned short u) {
    union { uint32_t u; float f; } v; v.u = ((uint32_t)u) << 16;
    return v.f;
}

__device__ inline bf16x4 cvt4(f32x4 a, float s) {
    bf16x4 r;
    r[0] = (short)f2bf(a[0] * s);
    r[1] = (short)f2bf(a[1] * s);
    r[2] = (short)f2bf(a[2] * s);
    r[3] = (short)f2bf(a[3] * s);
    return r;
}

#define GLOAD_LDS16(gsrc, ldst) \
    __builtin_amdgcn_global_load_lds((const __attribute__((address_space(1))) unsigned int*)(gsrc), \
        (__attribute__((address_space(3))) unsigned int*)(ldst), 16, 0, 0)

__device__ inline void publish_barrier() {
    asm volatile("s_waitcnt vmcnt(0)" ::: "memory");
    __builtin_amdgcn_sched_barrier(0);
    __builtin_amdgcn_s_barrier();
    __builtin_amdgcn_sched_barrier(0);
}
__device__ inline void gate8() {
    asm volatile("s_waitcnt vmcnt(8)" ::: "memory");
    __builtin_amdgcn_sched_barrier(0);
    __builtin_amdgcn_s_barrier();
    __builtin_amdgcn_sched_barrier(0);
}
__device__ inline void gate6() {
    asm volatile("s_waitcnt vmcnt(6)" ::: "memory");
    __builtin_amdgcn_sched_barrier(0);
    __builtin_amdgcn_s_barrier();
    __builtin_amdgcn_sched_barrier(0);
}
__device__ inline void gate2() {
    asm volatile("s_waitcnt vmcnt(2)" ::: "memory");
    __builtin_amdgcn_sched_barrier(0);
    __builtin_amdgcn_s_barrier();
    __builtin_amdgcn_sched_barrier(0);
}
__device__ inline void gate0() {
    asm volatile("s_waitcnt vmcnt(0)" ::: "memory");
    __builtin_amdgcn_sched_barrier(0);
    __builtin_amdgcn_s_barrier();
    __builtin_amdgcn_sched_barrier(0);
}

// ---------------------------------------------------------------------------
// Kernel 0: fused casts (r16-proven flat grid; r17's grid-stride bundle
// suspected -8us regression — de-bundled back).
// Blocks [0,16384): x fp32->bf16. Blocks [16384,17152): W (Wq pre-scaled).
// ---------------------------------------------------------------------------
__global__ __launch_bounds__(256) void cast_all(const float* __restrict__ x,
                                                const float* __restrict__ Wq,
                                                const float* __restrict__ Wk,
                                                const float* __restrict__ Wv,
                                                unsigned short* __restrict__ xb,
                                                unsigned short* __restrict__ Wb)
{
    int bx = blockIdx.x;
    if (bx < 16384) {
        size_t idx = (size_t)bx * 256 + threadIdx.x;
        size_t base = idx * 8;
        f32x4 a = *(const f32x4*)(x + base);
        f32x4 b = *(const f32x4*)(x + base + 4);
        bf16x4 lo = cvt4(a, 1.0f), hi = cvt4(b, 1.0f);
        bf16x8 o = {lo[0], lo[1], lo[2], lo[3], hi[0], hi[1], hi[2], hi[3]};
        *(bf16x8*)(xb + base) = o;
    } else {
        size_t idx = (size_t)(bx - 16384) * 256 + threadIdx.x;  // 0..196607
        int o = (int)(idx >> 16);
        size_t rem = idx & 65535;
        const float* W = (o == 0) ? Wq : (o == 1) ? Wk : Wv;
        float s = (o == 0) ? SCALE : 1.0f;
        size_t base = rem * 8;
        f32x4 a = *(const f32x4*)(W + base);
        f32x4 b = *(const f32x4*)(W + base + 4);
        bf16x4 lo = cvt4(a, s), hi = cvt4(b, s);
        bf16x8 out = {lo[0], lo[1], lo[2], lo[3], hi[0], hi[1], hi[2], hi[3]};
        *(bf16x8*)(Wb + (size_t)o * 524288 + base) = out;
    }
}

// ---------------------------------------------------------------------------
// Kernel 1: q/k/v projection v6c (r18-proven, 106.4 us, MfmaUtil 41%).
// 2 barriers/K-tile, counted vmcnt, 16x16x32 MFMA (32x32 switch REVERTED:
// its 32-row frag reads 4-way-conflict the 8-slot XOR swizzle — bank
// conflicts 2.6e5 -> 9.7e6, +6 us). V output (o==2): LDS-transpose epilogue.
// ---------------------------------------------------------------------------
__global__ __launch_bounds__(512, 2) void qkv_proj6c(
    const unsigned short* __restrict__ xb,
    const unsigned short* __restrict__ Wb,
    const float* __restrict__ bq, const float* __restrict__ bk, const float* __restrict__ bv,
    unsigned short* __restrict__ qkv,     // q at 0, k at MAT
    unsigned short* __restrict__ vt)      // [b][d][l]
{
    __shared__ __align__(16) unsigned short AL[2][2][8192];
    __shared__ __align__(16) unsigned short BL[2][2][8192];

    const int o = blockIdx.y;
    const float* bias = (o == 0) ? bq : (o == 1) ? bk : bv;
    const float wscale = (o == 0) ? SCALE : 1.0f;
    const unsigned short* W = Wb + (size_t)o * 524288;
    unsigned short* out = qkv + (size_t)o * MAT;

    int wg = blockIdx.x;
    wg = (wg & 7) * 32 + (wg >> 3);
    const int mt = wg >> 1, nt = wg & 1;
    const int rowbase = mt * 256;
    const int colbase = nt * 256;

    const int tid  = threadIdx.x;
    const int lane = tid & 63;
    const int w    = tid >> 6;
    const int wm   = w >> 2;
    const int wn   = w & 3;
    const int l15  = lane & 15, l4 = lane >> 4;
    const int rxor = l15 & 7;

    const int r8   = lane >> 3;
    const int swch = (lane & 7) ^ r8;

    const char* xpanel = (const char*)(xb + (size_t)rowbase * DM);
    const char* wpanel = (const char*)(W  + (size_t)colbase * DM);

    #define STAGE_HALF(panel, T, H, slot) do {                                   \
        _Pragma("unroll")                                                        \
        for (int i2 = 0; i2 < 2; ++i2) {                                         \
            int grp = i2 * 8 + w;                                                \
            GLOAD_LDS16((panel) + ((size_t)((H) * 128 + grp * 8 + r8) * 2048)    \
                            + (size_t)(T) * 128 + swch * 16,                     \
                        (char*)(slot) + grp * 1024);                             \
        }                                                                        \
    } while (0)

    #define RDA(base, mf4, ks) (*(const bf16x8*)((base) + (wm * 64 + (mf4) * 16 + l15) * 128 \
                            + ((((ks) * 4 + l4) ^ rxor) << 4)))
    #define RDB(base, nfl, ks) (*(const bf16x8*)((base) + (wn * 32 + (nfl) * 16 + l15) * 128 \
                            + ((((ks) * 4 + l4) ^ rxor) << 4)))

    f32x4 acc[8][4];
    #pragma unroll
    for (int i = 0; i < 8; ++i)
        #pragma unroll
        for (int j = 0; j < 4; ++j)
            acc[i][j] = (f32x4){0.f, 0.f, 0.f, 0.f};

    bf16x8 aF[4][2], bF[4][2];

    STAGE_HALF(xpanel, 0, 0, &AL[0][0][0]);   // A0(0)
    STAGE_HALF(wpanel, 0, 0, &BL[0][0][0]);   // B0(0)
    STAGE_HALF(wpanel, 0, 1, &BL[0][1][0]);   // B1(0)
    STAGE_HALF(xpanel, 0, 1, &AL[0][1][0]);   // A1(0)

    for (int t = 0; t < 16; ++t) {
        const int c = t & 1, cn = c ^ 1;
        const char* A0b = (const char*)&AL[c][0][0];
        const char* A1b = (const char*)&AL[c][1][0];
        const char* B0b = (const char*)&BL[c][0][0];
        const char* B1b = (const char*)&BL[c][1][0];
        const bool st = (t < 15);

        // ---- phase 0+1: (A0,B0) + (A0,B1) ----
        if (st) {
            STAGE_HALF(xpanel, t + 1, 0, &AL[cn][0][0]);
            STAGE_HALF(wpanel, t + 1, 0, &BL[cn][0][0]);
            gate6();
        } else gate2();
        #pragma unroll
        for (int ks = 0; ks < 2; ++ks) {
            #pragma unroll
            for (int mf = 0; mf < 4; ++mf) aF[mf][ks] = RDA(A0b, mf, ks);
            bF[0][ks] = RDB(B0b, 0, ks);
            bF[1][ks] = RDB(B0b, 1, ks);
            bF[2][ks] = RDB(B1b, 0, ks);
            bF[3][ks] = RDB(B1b, 1, ks);
        }
        #pragma unroll
        for (int ks = 0; ks < 2; ++ks)
            #pragma unroll
            for (int nf = 0; nf < 4; ++nf)
                #pragma unroll
                for (int mf = 0; mf < 4; ++mf)
                    acc[mf][nf] = __builtin_amdgcn_mfma_f32_16x16x32_bf16(aF[mf][ks], bF[nf][ks], acc[mf][nf], 0, 0, 0);

        // ---- phase 2+3: (A1,B0) + (A1,B1) ----
        if (st) {
            STAGE_HALF(wpanel, t + 1, 1, &BL[cn][1][0]);
            STAGE_HALF(xpanel, t + 1, 1, &AL[cn][1][0]);
            gate8();
        } else gate0();
        #pragma unroll
        for (int ks = 0; ks < 2; ++ks)
            #pragma unroll
            for (int mf = 0; mf < 4; ++mf) aF[mf][ks] = RDA(A1b, mf, ks);
        #pragma unroll
        for (int ks = 0; ks < 2; ++ks)
            #pragma unroll
            for (int nf = 0; nf < 4; ++nf)
                #pragma unroll
                for (int mf = 0; mf < 4; ++mf)
                    acc[4 + mf][nf] = __builtin_amdgcn_mfma_f32_16x16x32_bf16(aF[mf][ks], bF[nf][ks], acc[4 + mf][nf], 0, 0, 0);
    }
    #undef STAGE_HALF
    #undef RDA
    #undef RDB

    if (o != 2) {
        #pragma unroll
        for (int nf = 0; nf < 4; ++nf) {
            int col = colbase + ((nf < 2) ? wn * 32 + nf * 16 : 128 + wn * 32 + (nf - 2) * 16) + l15;
            float bv_ = bias[col] * wscale;
            #pragma unroll
            for (int mf = 0; mf < 8; ++mf) {
                int row0 = rowbase + ((mf < 4) ? wm * 64 + mf * 16 : 128 + wm * 64 + (mf - 4) * 16) + l4 * 4;
                #pragma unroll
                for (int r = 0; r < 4; ++r)
                    out[(size_t)(row0 + r) * DD + col] = f2bf(acc[mf][nf][r] + bv_);
            }
        }
    } else {
        // ---- V epilogue: transpose 256x256 tile via LDS -> vt[b][d][l] ----
        unsigned short* ldsT = (unsigned short*)&AL[0][0][0];
        const int bidx  = rowbase >> 10;
        const int lbase = rowbase & 1023;
        #pragma unroll
        for (int p = 0; p < 4; ++p) {
            __syncthreads();
            #pragma unroll
            for (int nf = 0; nf < 4; ++nf) {
                int base16 = (nf < 2) ? wn * 32 + nf * 16 : 128 + wn * 32 + (nf - 2) * 16;
                if (base16 >= p * 64 && base16 < p * 64 + 64) {
                    int cc = base16 - p * 64 + l15;
                    float bv_ = bias[colbase + base16 + l15];
                    #pragma unroll
                    for (int mf = 0; mf < 8; ++mf) {
                        int rowl = ((mf < 4) ? wm * 64 + mf * 16 : 128 + wm * 64 + (mf - 4) * 16) + l4 * 4;
                        bf16x4 v4;
                        #pragma unroll
                        for (int r = 0; r < 4; ++r)
                            v4[r] = (short)f2bf(acc[mf][nf][r] + bv_);
                        *(bf16x4*)&ldsT[cc * 264 + rowl] = v4;
                    }
                }
            }
            __syncthreads();
            #pragma unroll
            for (int it = 0; it < 4; ++it) {
                int uu = tid + it * 512;
                int cc = uu >> 5;
                int r0 = (uu & 31) * 8;
                bf16x8 val = *(const bf16x8*)&ldsT[cc * 264 + r0];
                int dg = colbase + p * 64 + cc;
                *(bf16x8*)(vt + ((size_t)(bidx * DD + dg)) * LL + lbase + r0) = val;
            }
        }
    }
}

// ---------------------------------------------------------------------------
// Kernel 3: S = q . k^T, lower-triangle 128x128 tiles (unchanged).
// ---------------------------------------------------------------------------
__global__ __launch_bounds__(256, 2) void sgemm_qk(
    const unsigned short* __restrict__ qkv,
    unsigned short* __restrict__ S)
{
    __shared__ __align__(16) unsigned short At[2][8192];
    __shared__ __align__(16) unsigned short Bt[2][8192];

    int wg = blockIdx.x;
    wg = (wg & 7) * 144 + (wg >> 3);
    const int b = wg / 36;
    const int t36 = wg % 36;
    int mt = 0, accq = 0;
    while (accq + mt + 1 <= t36) { ++mt; accq += mt; }
    const int nt = t36 - accq;

    const int tid  = threadIdx.x;
    const int lane = tid & 63;
    const int w    = tid >> 6;
    const int wr   = (w >> 1) * 64;
    const int wc   = (w & 1) * 64;
    const int l15  = lane & 15, l4 = lane >> 4;

    const int r8   = lane >> 3;
    const int swch = (lane & 7) ^ r8;

    const unsigned short* q = qkv;
    const unsigned short* k = qkv + MAT;
    const char* apanel = (const char*)(q + ((size_t)(b * LL) + mt * 128) * DD);
    const char* bpanel = (const char*)(k + ((size_t)(b * LL) + nt * 128) * DD);

    f32x4 acc[4][4];
    #pragma unroll
    for (int i = 0; i < 4; ++i)
        #pragma unroll
        for (int j = 0; j < 4; ++j)
            acc[i][j] = (f32x4){0.f, 0.f, 0.f, 0.f};

    #define STAGE_QK(KK, BUF) do {                                               \
        _Pragma("unroll")                                                        \
        for (int i2 = 0; i2 < 4; ++i2) {                                         \
            int grp = i2 * 4 + w;                                                \
            size_t rowoff = (size_t)(grp * 8 + r8) * 1024 + (KK) * 2 + swch * 16;\
            GLOAD_LDS16(apanel + rowoff, (char*)&At[BUF][0] + grp * 1024);       \
            GLOAD_LDS16(bpanel + rowoff, (char*)&Bt[BUF][0] + grp * 1024);       \
        }                                                                        \
    } while (0)

    STAGE_QK(0, 0);
    __syncthreads();

    for (int t = 0; t < 8; ++t) {
        const int cur = t & 1;
        if (t < 7) STAGE_QK((t + 1) * 64, cur ^ 1);

        const char* Ab = (const char*)&At[cur][0];
        const char* Bb = (const char*)&Bt[cur][0];
        #pragma unroll
        for (int ks = 0; ks < 2; ++ks) {
            bf16x8 af[4], bf_[4];
            const int ch = (ks * 4 + l4) ^ (l15 & 7);
            #pragma unroll
            for (int m = 0; m < 4; ++m)
                af[m] = *(const bf16x8*)(Ab + (wr + m * 16 + l15) * 128 + (ch << 4));
            #pragma unroll
            for (int n = 0; n < 4; ++n)
                bf_[n] = *(const bf16x8*)(Bb + (wc + n * 16 + l15) * 128 + (ch << 4));
            #pragma unroll
            for (int n = 0; n < 4; ++n)
                #pragma unroll
                for (int m = 0; m < 4; ++m)
                    acc[m][n] = __builtin_amdgcn_mfma_f32_16x16x32_bf16(af[m], bf_[n], acc[m][n], 0, 0, 0);
        }

        if (t < 7) publish_barrier();
    }
    #undef STAGE_QK

    unsigned short* sp = S + ((size_t)(b * LL) + mt * 128) * LL + nt * 128;
    #pragma unroll
    for (int n = 0; n < 4; ++n) {
        int col = wc + n * 16 + l15;
        #pragma unroll
        for (int m = 0; m < 4; ++m) {
            int row0 = wr + m * 16 + l4 * 4;
            #pragma unroll
            for (int r = 0; r < 4; ++r)
                sp[(size_t)(row0 + r) * LL + col] = f2bf(acc[m][n][r]);
        }
    }
}

// ---------------------------------------------------------------------------
// Kernel 4: row softmax v2 (unchanged).
// ---------------------------------------------------------------------------
__global__ __launch_bounds__(256) void softmax_rows(
    const unsigned short* __restrict__ S,
    const int* __restrict__ mask,
    unsigned short* __restrict__ P)
{
    __shared__ float mbias[1024];
    const int rc = blockIdx.x, b = blockIdx.y;
    const int tid = threadIdx.x, lane = tid & 63, w = tid >> 6;

    {
        const int* mp = mask + b * LL;
        #pragma unroll
        for (int j = 0; j < 4; ++j)
            mbias[tid * 4 + j] = mp[tid * 4 + j] ? 0.0f : -1e30f;
    }
    __syncthreads();

    const int j0 = lane * 16;
    const int limit = ((rc >> 2) + 1) << 7;
    for (int i = 0; i < 8; ++i) {
        const int r = rc * 32 + i * 4 + w;
        const unsigned short* srow = S + ((size_t)(b * LL) + r) * LL;

        bf16x8 v0 = {0,0,0,0,0,0,0,0}, v1 = {0,0,0,0,0,0,0,0};
        if (j0 <= r)     v0 = *(const bf16x8*)(srow + j0);
        if (j0 + 8 <= r) v1 = *(const bf16x8*)(srow + j0 + 8);

        float s[16];
        #pragma unroll
        for (int e = 0; e < 8; ++e) {
            int j = j0 + e;
            s[e]     = (j <= r)     ? bf2f((unsigned short)v0[e]) + mbias[j]     : -3e38f;
            s[8 + e] = (j + 8 <= r) ? bf2f((unsigned short)v1[e]) + mbias[j + 8] : -3e38f;
        }
        float mx = s[0];
        #pragma unroll
        for (int e = 1; e < 16; ++e) mx = fmaxf(mx, s[e]);
        mx = fmaxf(mx, __shfl_xor(mx, 1));
        mx = fmaxf(mx, __shfl_xor(mx, 2));
        mx = fmaxf(mx, __shfl_xor(mx, 4));
        mx = fmaxf(mx, __shfl_xor(mx, 8));
        mx = fmaxf(mx, __shfl_xor(mx, 16));
        mx = fmaxf(mx, __shfl_xor(mx, 32));

        float p[16], ls = 0.f;
        #pragma unroll
        for (int e = 0; e < 16; ++e) { p[e] = __expf(s[e] - mx); ls += p[e]; }
        ls += __shfl_xor(ls, 1);
        ls += __shfl_xor(ls, 2);
        ls += __shfl_xor(ls, 4);
        ls += __shfl_xor(ls, 8);
        ls += __shfl_xor(ls, 16);
        ls += __shfl_xor(ls, 32);
        const float inv = 1.0f / ls;

        if (j0 < limit) {
            bf16x8 o0, o1;
            #pragma unroll
            for (int e = 0; e < 8; ++e) {
                o0[e] = (short)f2bf(p[e] * inv);
                o1[e] = (short)f2bf(p[8 + e] * inv);
            }
            unsigned short* prow = P + ((size_t)(b * LL) + r) * LL;
            *(bf16x8*)(prow + j0)     = o0;
            *(bf16x8*)(prow + j0 + 8) = o1;
        }
    }
}

// ---------------------------------------------------------------------------
// Kernel 5: O = relu(P . V) via vt (unchanged).
// ---------------------------------------------------------------------------
__global__ __launch_bounds__(256, 2) void pv_gemm(
    const unsigned short* __restrict__ P,
    const unsigned short* __restrict__ vt,
    float* __restrict__ outp)
{
    __shared__ __align__(16) unsigned short At[2][8192];
    __shared__ __align__(16) unsigned short Bt[2][8192];

    int wg = blockIdx.x;
    wg = (wg & 7) * 128 + (wg >> 3);
    const int b  = wg >> 5;
    const int rr = wg & 31;
    const int idx = rr >> 2;
    const int rt = (idx & 1) ? ((idx - 1) >> 1) : (7 - (idx >> 1));  // 7,0,6,1,5,2,4,3
    const int ct = rr & 3;

    const int tid  = threadIdx.x;
    const int lane = tid & 63;
    const int w    = tid >> 6;
    const int wr   = (w >> 1) * 64;
    const int wc   = (w & 1) * 64;
    const int l15  = lane & 15, l4 = lane >> 4;

    const int r8   = lane >> 3;
    const int swch = (lane & 7) ^ r8;

    const char* apanel = (const char*)(P  + ((size_t)(b * LL) + rt * 128) * LL);
    const char* bpanel = (const char*)(vt + ((size_t)(b * DD) + ct * 128) * LL);

    const int NT = (rt + 1) * 2;

    f32x4 acc[4][4];
    #pragma unroll
    for (int i = 0; i < 4; ++i)
        #pragma unroll
        for (int j = 0; j < 4; ++j)
            acc[i][j] = (f32x4){0.f, 0.f, 0.f, 0.f};

    #define STAGE_PV(KK, BUF) do {                                               \
        _Pragma("unroll")                                                        \
        for (int i2 = 0; i2 < 4; ++i2) {                                         \
            int grp = i2 * 4 + w;                                                \
            size_t rowoff = (size_t)(grp * 8 + r8) * 2048 + (KK) * 2 + swch * 16;\
            GLOAD_LDS16(apanel + rowoff, (char*)&At[BUF][0] + grp * 1024);       \
            GLOAD_LDS16(bpanel + rowoff, (char*)&Bt[BUF][0] + grp * 1024);       \
        }                                                                        \
    } while (0)

    STAGE_PV(0, 0);
    __syncthreads();

    for (int t = 0; t < NT; ++t) {
        const int cur = t & 1;
        if (t < NT - 1) STAGE_PV((t + 1) * 64, cur ^ 1);

        const char* Ab = (const char*)&At[cur][0];
        const char* Bb = (const char*)&Bt[cur][0];
        #pragma unroll
        for (int ks = 0; ks < 2; ++ks) {
            bf16x8 af[4], bf_[4];
            const int ch = (ks * 4 + l4) ^ (l15 & 7);
            #pragma unroll
            for (int m = 0; m < 4; ++m)
                af[m] = *(const bf16x8*)(Ab + (wr + m * 16 + l15) * 128 + (ch << 4));
            #pragma unroll
            for (int n = 0; n < 4; ++n)
                bf_[n] = *(const bf16x8*)(Bb + (wc + n * 16 + l15) * 128 + (ch << 4));
            #pragma unroll
            for (int n = 0; n < 4; ++n)
                #pragma unroll
                for (int m = 0; m < 4; ++m)
                    acc[m][n] = __builtin_amdgcn_mfma_f32_16x16x32_bf16(af[m], bf_[n], acc[m][n], 0, 0, 0);
        }

        if (t < NT - 1) publish_barrier();
    }
    #undef STAGE_PV

    float* op = outp + ((size_t)(b * LL) + rt * 128) * DD + ct * 128;
    #pragma unroll
    for (int n = 0; n < 4; ++n) {
        int col = wc + n * 16 + l15;
        #pragma unroll
        for (int m = 0; m < 4; ++m) {
            int row0 = wr + m * 16 + l4 * 4;
            #pragma unroll
            for (int r = 0; r < 4; ++r)
                op[(size_t)(row0 + r) * DD + col] = fmaxf(acc[m][n][r], 0.f);
        }
    }
}

extern "C" void kernel_launch(void* const* d_in, const int* in_sizes, int n_in,
                              void* d_out, int out_size, void* d_ws, size_t ws_size,
                              hipStream_t stream) {
    const float* x  = (const float*)d_in[0];
    const float* Wq = (const float*)d_in[1];
    const float* bq = (const float*)d_in[2];
    const float* Wk = (const float*)d_in[3];
    const float* bk = (const float*)d_in[4];
    const float* Wv = (const float*)d_in[5];
    const float* bv = (const float*)d_in[6];
    const int* mask = (const int*)d_in[7];

    unsigned short* qkv = (unsigned short*)d_ws;          // q | k (2 x 32MB)
    unsigned short* vtp = qkv + 2 * MAT;                  // vt [b][d][l] (32MB)
    unsigned short* Wb  = qkv + 3 * MAT;                  // W bf16 (3MB)
    unsigned short* xb  = (unsigned short*)d_out;         // x bf16 (64MB), dead after proj
    unsigned short* S   = (unsigned short*)d_out;         // S bf16 (64MB), overwrites xb
    unsigned short* Pp  = qkv;                            // P bf16 over q+k (dead)
    float* out = (float*)d_out;                           // final O overwrites S

    cast_all<<<17152, 256, 0, stream>>>(x, Wq, Wk, Wv, xb, Wb);
    qkv_proj6c<<<dim3(256, 3), 512, 0, stream>>>(xb, Wb, bq, bk, bv, qkv, vtp);
    sgemm_qk<<<dim3(1152), 256, 0, stream>>>(qkv, S);
    softmax_rows<<<dim3(32, 32), 256, 0, stream>>>(S, mask, Pp);
    pv_gemm<<<dim3(1024), 256, 0, stream>>>(Pp, vtp, out);
}